// Round 2
// baseline (66.906 us; speedup 1.0000x reference)
//
#include <hip/hip_runtime.h>

// Problem constants (from reference): V=16, T=2048, D=1, K=16
#define NV 16
#define NT 2048
#define NK 16
#define NROWS (NT - NK)   // 2032 output rows per video

// One thread per output row i in [K, T).
//
// t is sorted along T with D==1, so score -(t_i - t_j)^2 is nondecreasing in
// j over causal j<i: top-k is the trailing window, reordered by lax.top_k's
// stable tie rule (equal scores -> ascending index; boundary tie-group
// truncated to its lowest indices). Ties in score <=> bit-equal timestamps
// (subtraction exact here, squaring injective on distinct diffs).
//
// Fast path (t[i-17] != t[i-16], i.e. no tie-run crosses the window
// boundary): selected set is exactly {i-16..i-1}. Load those 16 values with
// independent global loads (static register indexing only), build a 15-bit
// adjacent-equality mask, emit runs directly to global. No LDS, no private
// array -> no scratch, one memory-latency wait on the critical path.
__global__ __launch_bounds__(64) void topk_rows_kernel(
    const float* __restrict__ t,      // (V, T, 1) float32, sorted along T
    const int* __restrict__ mask,     // (V, T, 1) prefix mask (int32)
    int* __restrict__ out)            // (V, T-K, K) int32
{
    const int gid = blockIdx.x * 64 + (int)threadIdx.x;
    if (gid >= NV * NROWS) return;
    const int v = gid / NROWS;
    const int i = NK + (gid - v * NROWS);

    int* orow = out + (size_t)gid * NK;

    // valid iff mask[v][i] (mask IS the arange(T) < seq_len prefix mask)
    if (mask[v * NT + i] == 0) {
        #pragma unroll
        for (int s = 0; s < NK; ++s) orow[s] = 0;
        return;
    }

    const float* tv = t + v * NT;

    // w[m] = tv[i-1-m]: backward-order window, static indices -> registers,
    // 16 independent loads batched behind a single waitcnt.
    float w[NK];
    #pragma unroll
    for (int m = 0; m < NK; ++m) w[m] = tv[i - 1 - m];

    // Does the run containing i-16 extend below the window? (rare)
    const bool slow = (i >= NK + 1) && (tv[i - NK - 1] == w[NK - 1]);

    if (!slow) {
        // 15-bit adjacent-equality mask over backward positions.
        unsigned eqm = 0u;
        #pragma unroll
        for (int m = 0; m < NK - 1; ++m)
            eqm |= (w[m + 1] == w[m]) ? (1u << m) : 0u;

        if (eqm == 0u) {
            // All-unique (dominant case): plain descending indices.
            #pragma unroll
            for (int s = 0; s < NK; ++s) orow[s] = i - 1 - s;
            return;
        }

        // Runs in backward-position space: run [m..b] occupies output slots
        // m..b; ascending index within run. Scalar registers + direct global
        // stores only.
        int m = 0;
        while (m < NK) {
            int b = m;
            while (b < NK - 1 && ((eqm >> b) & 1u)) ++b;
            for (int p = b; p >= m; --p)
                orow[m + (b - p)] = i - 1 - p;
            m = b + 1;
        }
        return;
    }

    // Slow path: tie-run crosses the window boundary. Full backward run walk
    // over global memory (L2-resident), direct stores.
    int slot = 0;
    int j = i - 1;
    while (slot < NK && j >= 0) {
        const float val = tv[j];
        int p = j;
        while (p > 0 && tv[p - 1] == val) --p;
        const int run = j - p + 1;
        const int take = (run < NK - slot) ? run : (NK - slot);
        for (int r = 0; r < take; ++r) orow[slot + r] = p + r;
        slot += take;
        j = p - 1;
    }
    for (; slot < NK; ++slot) orow[slot] = 0;  // unreachable (i >= K), safety
}

extern "C" void kernel_launch(void* const* d_in, const int* in_sizes, int n_in,
                              void* d_out, int out_size, void* d_ws, size_t ws_size,
                              hipStream_t stream) {
    const float* t    = (const float*)d_in[0];   // (V,T,1) float32
    const int*   mask = (const int*)d_in[1];     // (V,T,1) bool as int32
    // d_in[2] is k == 16, compile-time constant here.
    int* out = (int*)d_out;                      // (V, T-K, K) int32

    const int total = NV * NROWS;                // 32512
    const int blocks = (total + 63) / 64;        // 508 -> ~2 blocks per CU
    topk_rows_kernel<<<dim3(blocks), dim3(64), 0, stream>>>(t, mask, out);
}